// Round 1
// baseline (8747.036 us; speedup 1.0000x reference)
//
#include <hip/hip_runtime.h>

#define S_LEN 256
#define B_SZ 64
#define I_SZ 512
#define H_SZ 1024
#define N1_SZ 4096   // 4 gates * H

typedef __bf16 bf16x8 __attribute__((ext_vector_type(8)));
typedef float f32x4 __attribute__((ext_vector_type(4)));

__device__ __forceinline__ float sigmoidf_(float x){ return 1.f/(1.f + expf(-x)); }

// ---------------- prep kernels ----------------

// Pack gate weights W4[k][n] (n = g*1024+h, k in [0,1536)) into MFMA B-fragment order:
// W4p[((nt*48 + kb)*64 + lane)*8 + j] = W_g[k = kb*32 + (lane>>4)*8 + j][h], n = nt*16 + (lane&15)
__global__ __launch_bounds__(64) void pack_w4_k(const float* __restrict__ Wf, const float* __restrict__ Wi,
                                                const float* __restrict__ Wu, const float* __restrict__ Wo,
                                                __bf16* __restrict__ W4p){
  int blk = blockIdx.x;           // nt*48 + kb
  int nt = blk / 48, kb = blk % 48;
  int l = threadIdx.x;
  int n = nt*16 + (l & 15);
  int g = n >> 10, h = n & 1023;
  const float* W = (g==0)?Wf:((g==1)?Wi:((g==2)?Wu:Wo));
  int k0 = kb*32 + ((l>>4)<<3);
  __bf16 tmp[8];
#pragma unroll
  for (int j=0;j<8;j++) tmp[j] = (__bf16)W[(size_t)(k0+j)*H_SZ + h];
  *reinterpret_cast<bf16x8*>(W4p + ((size_t)blk*64 + l)*8) = *reinterpret_cast<bf16x8*>(tmp);
}

// Pack Wc[0:1024][:] similarly: 64 n-tiles, 32 k-blocks
__global__ __launch_bounds__(64) void pack_wc_k(const float* __restrict__ Wc, __bf16* __restrict__ Wcp){
  int blk = blockIdx.x;           // nt*32 + kb
  int nt = blk / 32, kb = blk % 32;
  int l = threadIdx.x;
  int n = nt*16 + (l & 15);
  int k0 = kb*32 + ((l>>4)<<3);
  __bf16 tmp[8];
#pragma unroll
  for (int j=0;j<8;j++) tmp[j] = (__bf16)Wc[(size_t)(k0+j)*H_SZ + n];
  *reinterpret_cast<bf16x8*>(Wcp + ((size_t)blk*64 + l)*8) = *reinterpret_cast<bf16x8*>(tmp);
}

__global__ void cast_x_k(const float* __restrict__ x, __bf16* __restrict__ xb, int n){
  int stride = gridDim.x * blockDim.x * 4;
  for (int i = (blockIdx.x*blockDim.x + threadIdx.x)*4; i < n; i += stride){
    float4 v = *reinterpret_cast<const float4*>(x + i);
    __bf16 o[4] = {(__bf16)v.x, (__bf16)v.y, (__bf16)v.z, (__bf16)v.w};
    *reinterpret_cast<uint2*>(xb + i) = *reinterpret_cast<const uint2*>(o);
  }
}

__global__ void init_state_k(__bf16* __restrict__ hxb, float* __restrict__ cxp){
  int i = blockIdx.x*blockDim.x + threadIdx.x;   // 65536 threads
  hxb[i] = (__bf16)0.f;
  cxp[i] = 0.f;
}

// ---------------- per-step kernels ----------------

// K1: pre = [x_s, hx] @ W4 + bias -> activations + qgate z
// grid 256 blocks (one 16-col n-tile each), 4 waves = 4 M-tiles (64 batch rows)
__global__ __launch_bounds__(256) void step_pre_k(
    const __bf16* __restrict__ xs,     // x for this step, (64,512) bf16
    const __bf16* __restrict__ hxb,    // (64,1024) bf16
    const __bf16* __restrict__ W4p,
    const float* __restrict__ bfv, const float* __restrict__ biv,
    const float* __restrict__ buv, const float* __restrict__ bov,
    const float* __restrict__ pf, const float* __restrict__ pi_q,
    const float* __restrict__ pu, const float* __restrict__ po,
    __bf16* __restrict__ act,          // (4,64,1024) bf16
    float* __restrict__ zact)          // (4,64) f32
{
  __shared__ float pre4[64][4];
  int nb = blockIdx.x;
  int wave = threadIdx.x >> 6;
  int l = threadIdx.x & 63;
  int arow = wave*16 + (l & 15);       // batch row for A-fragment
  int ksub = (l >> 4) * 8;
  const __bf16* xrow = xs  + (size_t)arow*I_SZ + ksub;
  const __bf16* hrow = hxb + (size_t)arow*H_SZ + ksub;
  const __bf16* bp = W4p + ((size_t)nb*48*64 + l)*8;
  f32x4 acc[4] = {{0,0,0,0},{0,0,0,0},{0,0,0,0},{0,0,0,0}};
#pragma unroll 4
  for (int kb=0;kb<16;kb++){           // x part: k in [0,512)
    bf16x8 a = *reinterpret_cast<const bf16x8*>(xrow + kb*32);
    bf16x8 b = *reinterpret_cast<const bf16x8*>(bp + (size_t)kb*512);
    acc[kb&3] = __builtin_amdgcn_mfma_f32_16x16x32_bf16(a, b, acc[kb&3], 0,0,0);
  }
#pragma unroll 4
  for (int kb=16;kb<48;kb++){          // hx part: k in [512,1536)
    bf16x8 a = *reinterpret_cast<const bf16x8*>(hrow + (kb-16)*32);
    bf16x8 b = *reinterpret_cast<const bf16x8*>(bp + (size_t)kb*512);
    acc[kb&3] = __builtin_amdgcn_mfma_f32_16x16x32_bf16(a, b, acc[kb&3], 0,0,0);
  }
  f32x4 r = (acc[0]+acc[1])+(acc[2]+acc[3]);
  int n = nb*16 + (l & 15);
  int g = n >> 10, h = n & 1023;
  const float* bias = (g==0)?bfv:((g==1)?biv:((g==2)?buv:bov));
  float bv = bias[h];
  bool isU = (g==2);
  float pr[4];
#pragma unroll
  for (int rr=0;rr<4;rr++){
    int b = wave*16 + ((l>>4)<<2) + rr;   // D row -> batch
    float p = r[rr] + bv;
    pr[rr] = p;
    float a = isU ? tanhf(p) : sigmoidf_(p);
    act[((size_t)g*B_SZ + b)*H_SZ + h] = (__bf16)a;
  }
  // qgate: only blocks owning columns h in [0,16) of each gate (nb % 64 == 0)
  if ((nb & 63) == 0){
    if ((l & 15) < 4){
#pragma unroll
      for (int rr=0;rr<4;rr++){
        int b = wave*16 + ((l>>4)<<2) + rr;
        pre4[b][l & 3] = pr[rr];
      }
    }
    __syncthreads();
    int t = threadIdx.x;
    if (t < 64){
      const float* p = (g==0)?pf:((g==1)?pi_q:((g==2)?pu:po));
      float th = pre4[t][0]*p[0] + pre4[t][1]*p[1] + pre4[t][2]*p[2] + pre4[t][3]*p[3];
      float z = cosf(2.f*th);
      zact[g*B_SZ + t] = isU ? z : sigmoidf_(z);
    }
  }
}

// K2: comb for all 4 gates for a 16-col h-slice + LSTM cell update
// grid 64 blocks, 4 waves = 4 M-tiles
__global__ __launch_bounds__(256) void step_comb_k(
    const __bf16* __restrict__ act, const __bf16* __restrict__ Wcp,
    const float* __restrict__ WcLast,  // Wc row 1024
    const float* __restrict__ bc, const float* __restrict__ zact,
    float* __restrict__ cx, __bf16* __restrict__ hxb,
    float* __restrict__ outs,          // outputs[s], (64,1024) f32
    float* __restrict__ hx_out, float* __restrict__ cx_out, int last)
{
  int nb = blockIdx.x;                 // h-tile 0..63
  int wave = threadIdx.x >> 6;
  int l = threadIdx.x & 63;
  int arow = wave*16 + (l & 15);
  int ksub = (l >> 4) * 8;
  const __bf16* a0 = act + (size_t)arow*H_SZ + ksub;
  const __bf16* bp = Wcp + ((size_t)nb*32*64 + l)*8;
  f32x4 acc[4] = {{0,0,0,0},{0,0,0,0},{0,0,0,0},{0,0,0,0}};
#pragma unroll 4
  for (int kb=0;kb<32;kb++){
    bf16x8 b  = *reinterpret_cast<const bf16x8*>(bp + (size_t)kb*512);
    bf16x8 aF = *reinterpret_cast<const bf16x8*>(a0 + kb*32);
    bf16x8 aI = *reinterpret_cast<const bf16x8*>(a0 + 1*B_SZ*H_SZ + kb*32);
    bf16x8 aU = *reinterpret_cast<const bf16x8*>(a0 + 2*B_SZ*H_SZ + kb*32);
    bf16x8 aO = *reinterpret_cast<const bf16x8*>(a0 + 3*B_SZ*H_SZ + kb*32);
    acc[0] = __builtin_amdgcn_mfma_f32_16x16x32_bf16(aF, b, acc[0], 0,0,0);
    acc[1] = __builtin_amdgcn_mfma_f32_16x16x32_bf16(aI, b, acc[1], 0,0,0);
    acc[2] = __builtin_amdgcn_mfma_f32_16x16x32_bf16(aU, b, acc[2], 0,0,0);
    acc[3] = __builtin_amdgcn_mfma_f32_16x16x32_bf16(aO, b, acc[3], 0,0,0);
  }
  int h = nb*16 + (l & 15);
  float wl = WcLast[h], bcv = bc[h];
#pragma unroll
  for (int rr=0;rr<4;rr++){
    int b = wave*16 + ((l>>4)<<2) + rr;
    float cf = acc[0][rr] + bcv + zact[       b]*wl;
    float ci = acc[1][rr] + bcv + zact[ 64 + b]*wl;
    float cu = acc[2][rr] + bcv + zact[128 + b]*wl;
    float co = acc[3][rr] + bcv + zact[192 + b]*wl;
    float fg = sigmoidf_(cf);
    float ig = sigmoidf_(ci);
    float gg = tanhf(cu);
    float og = sigmoidf_(co);
    size_t idx = (size_t)b*H_SZ + h;
    float cn = fg*cx[idx] + ig*gg;
    cx[idx] = cn;
    float hn = og*tanhf(cn);
    hxb[idx] = (__bf16)hn;
    outs[idx] = hn;
    if (last){ hx_out[idx] = hn; cx_out[idx] = cn; }
  }
}

// ---------------- launch ----------------

extern "C" void kernel_launch(void* const* d_in, const int* in_sizes, int n_in,
                              void* d_out, int out_size, void* d_ws, size_t ws_size,
                              hipStream_t stream){
  const float* inputs = (const float*)d_in[0];
  const float* Wf  = (const float*)d_in[1];
  const float* bf_ = (const float*)d_in[2];
  const float* Wi  = (const float*)d_in[3];
  const float* bi_ = (const float*)d_in[4];
  const float* Wu  = (const float*)d_in[5];
  const float* bu_ = (const float*)d_in[6];
  const float* Wo  = (const float*)d_in[7];
  const float* bo_ = (const float*)d_in[8];
  const float* pf  = (const float*)d_in[9];
  const float* piq = (const float*)d_in[10];
  const float* pu  = (const float*)d_in[11];
  const float* po  = (const float*)d_in[12];
  const float* Wc  = (const float*)d_in[13];
  const float* bc  = (const float*)d_in[14];
  float* out = (float*)d_out;

  __bf16* W4p = (__bf16*)d_ws;                        // 6,291,456 bf16
  __bf16* Wcp = W4p + (size_t)256*48*64*8;            // 1,048,576 bf16
  __bf16* xb  = Wcp + (size_t)64*32*64*8;             // 8,388,608 bf16
  __bf16* act = xb  + (size_t)S_LEN*B_SZ*I_SZ;        // 262,144 bf16
  __bf16* hxb = act + (size_t)4*B_SZ*H_SZ;            // 65,536 bf16
  float*  cx  = (float*)(hxb + (size_t)B_SZ*H_SZ);    // 65,536 f32
  float*  zact = cx + (size_t)B_SZ*H_SZ;              // 256 f32

  pack_w4_k<<<256*48, 64, 0, stream>>>(Wf, Wi, Wu, Wo, W4p);
  pack_wc_k<<<64*32, 64, 0, stream>>>(Wc, Wcp);
  cast_x_k<<<2048, 256, 0, stream>>>(inputs, xb, S_LEN*B_SZ*I_SZ);
  init_state_k<<<256, 256, 0, stream>>>(hxb, cx);

  const size_t SBH = (size_t)S_LEN*B_SZ*H_SZ;
  for (int s=0; s<S_LEN; s++){
    step_pre_k<<<256, 256, 0, stream>>>(xb + (size_t)s*B_SZ*I_SZ, hxb, W4p,
                                        bf_, bi_, bu_, bo_, pf, piq, pu, po, act, zact);
    step_comb_k<<<64, 256, 0, stream>>>(act, Wcp, Wc + (size_t)H_SZ*H_SZ, bc, zact,
                                        cx, hxb, out + (size_t)s*B_SZ*H_SZ,
                                        out + SBH, out + SBH + (size_t)B_SZ*H_SZ,
                                        (s==S_LEN-1) ? 1 : 0);
  }
}

// Round 2
// 8694.151 us; speedup vs baseline: 1.0061x; 1.0061x over previous
//
#include <hip/hip_runtime.h>

#define S_LEN 256
#define B_SZ 64
#define I_SZ 512
#define H_SZ 1024
#define NBLK 256

typedef __bf16 bf16x8 __attribute__((ext_vector_type(8)));
typedef float f32x4 __attribute__((ext_vector_type(4)));

__device__ __forceinline__ float sigmoidf_(float x){ return 1.f/(1.f + expf(-x)); }

// ---------------- prep kernels ----------------

// Pack gate weights W4[k][n] (n = g*1024+h, k in [0,1536)) into MFMA B-fragment order:
// W4p[((nt*48 + kb)*64 + lane)*8 + j] = W_g[k = kb*32 + (lane>>4)*8 + j][h], n = nt*16 + (lane&15)
__global__ __launch_bounds__(64) void pack_w4_k(const float* __restrict__ Wf, const float* __restrict__ Wi,
                                                const float* __restrict__ Wu, const float* __restrict__ Wo,
                                                __bf16* __restrict__ W4p){
  int blk = blockIdx.x;           // nt*48 + kb
  int nt = blk / 48, kb = blk % 48;
  int l = threadIdx.x;
  int n = nt*16 + (l & 15);
  int g = n >> 10, h = n & 1023;
  const float* W = (g==0)?Wf:((g==1)?Wi:((g==2)?Wu:Wo));
  int k0 = kb*32 + ((l>>4)<<3);
  __bf16 tmp[8];
#pragma unroll
  for (int j=0;j<8;j++) tmp[j] = (__bf16)W[(size_t)(k0+j)*H_SZ + h];
  *reinterpret_cast<bf16x8*>(W4p + ((size_t)blk*64 + l)*8) = *reinterpret_cast<bf16x8*>(tmp);
}

// Pack Wc[0:1024][:] similarly: 64 n-tiles, 32 k-blocks
__global__ __launch_bounds__(64) void pack_wc_k(const float* __restrict__ Wc, __bf16* __restrict__ Wcp){
  int blk = blockIdx.x;           // nt*32 + kb
  int nt = blk / 32, kb = blk % 32;
  int l = threadIdx.x;
  int n = nt*16 + (l & 15);
  int k0 = kb*32 + ((l>>4)<<3);
  __bf16 tmp[8];
#pragma unroll
  for (int j=0;j<8;j++) tmp[j] = (__bf16)Wc[(size_t)(k0+j)*H_SZ + n];
  *reinterpret_cast<bf16x8*>(Wcp + ((size_t)blk*64 + l)*8) = *reinterpret_cast<bf16x8*>(tmp);
}

__global__ void cast_x_k(const float* __restrict__ x, __bf16* __restrict__ xb, int n){
  int stride = gridDim.x * blockDim.x * 4;
  for (int i = (blockIdx.x*blockDim.x + threadIdx.x)*4; i < n; i += stride){
    float4 v = *reinterpret_cast<const float4*>(x + i);
    __bf16 o[4] = {(__bf16)v.x, (__bf16)v.y, (__bf16)v.z, (__bf16)v.w};
    *reinterpret_cast<uint2*>(xb + i) = *reinterpret_cast<const uint2*>(o);
  }
}

__global__ void init_h_k(__bf16* __restrict__ hxb){
  int i = blockIdx.x*blockDim.x + threadIdx.x;   // 65536 threads
  hxb[i] = (__bf16)0.f;
}

// ---------------- grid barrier (all 256 blocks resident: 1 block/CU forced by LDS) ----------------

__device__ __forceinline__ void grid_sync(unsigned* cnt, unsigned* gen){
  __syncthreads();
  if (threadIdx.x == 0){
    unsigned g0 = __hip_atomic_load(gen, __ATOMIC_RELAXED, __HIP_MEMORY_SCOPE_AGENT);
    unsigned a = __hip_atomic_fetch_add(cnt, 1u, __ATOMIC_ACQ_REL, __HIP_MEMORY_SCOPE_AGENT);
    if (a == (unsigned)(NBLK-1)){
      __hip_atomic_store(cnt, 0u, __ATOMIC_RELAXED, __HIP_MEMORY_SCOPE_AGENT);
      __hip_atomic_store(gen, g0+1u, __ATOMIC_RELEASE, __HIP_MEMORY_SCOPE_AGENT);
    } else {
      while (__hip_atomic_load(gen, __ATOMIC_RELAXED, __HIP_MEMORY_SCOPE_AGENT) == g0){
        __builtin_amdgcn_s_sleep(1);
      }
      __builtin_amdgcn_fence(__ATOMIC_ACQUIRE, "agent");
    }
  }
  __syncthreads();
}

// ---------------- persistent kernel: all 256 steps ----------------

__global__ __launch_bounds__(256, 1) void qlstm_persist_k(
    const __bf16* __restrict__ xb,    // (S,B,I) bf16
    __bf16* hxb,                      // (B,H) bf16 state (init 0)
    const __bf16* __restrict__ W4p, const __bf16* __restrict__ Wcp,
    const float* __restrict__ bfv, const float* __restrict__ biv,
    const float* __restrict__ buv, const float* __restrict__ bov,
    const float* __restrict__ pf, const float* __restrict__ piq,
    const float* __restrict__ pu, const float* __restrict__ po,
    const float* __restrict__ WcLast, const float* __restrict__ bc,
    __bf16* act, float* zact,
    float* __restrict__ out,          // outputs (S,B,H) + hx (B,H) + cx (B,H)
    unsigned* bar_cnt, unsigned* bar_gen)
{
  __shared__ __align__(16) __bf16 ldsW[48*64*8];    // 49152 B: phase-1 B frags (this block's n-tile)
  __shared__ __align__(16) __bf16 ldsWc[32*64*8];   // 32768 B: phase-2 Wc frags (this block's h-tile)
  __shared__ float gx[4][16][16];                   // gate exchange
  __shared__ float pre4[64][4];                     // qgate pre-activations

  const int tid = threadIdx.x;
  const int wave = tid >> 6;
  const int l = tid & 63;
  const int col = l & 15;
  const int ksub = (l >> 4) * 8;

  // ---- stage weights to LDS once ----
  {
    const __bf16* src = W4p + (size_t)blockIdx.x*48*64*8;
    for (int i = tid; i < 48*64; i += 256)
      *reinterpret_cast<bf16x8*>(&ldsW[(size_t)i*8]) = *reinterpret_cast<const bf16x8*>(src + (size_t)i*8);
    const int n16s = blockIdx.x >> 2;
    const __bf16* src2 = Wcp + (size_t)n16s*32*64*8;
    for (int i = tid; i < 32*64; i += 256)
      *reinterpret_cast<bf16x8*>(&ldsWc[(size_t)i*8]) = *reinterpret_cast<const bf16x8*>(src2 + (size_t)i*8);
  }

  // ---- per-thread constants ----
  // phase 1: block owns n-tile blockIdx.x (16 cols of 4096); wave = batch quarter
  const int n1 = blockIdx.x*16 + col;
  const int g1 = n1 >> 10;
  const int h1 = n1 & 1023;
  const float* bptr = (g1==0)?bfv:((g1==1)?biv:((g1==2)?buv:bov));
  const float bias1 = bptr[h1];
  const bool isU1 = (g1==2);
  const int arow1 = wave*16 + col;

  const bool isQ = ((blockIdx.x & 63) == 0);
  const int gq = blockIdx.x >> 6;
  float pq0=0.f,pq1=0.f,pq2=0.f,pq3=0.f;
  if (isQ){
    const float* pq = (gq==0)?pf:((gq==1)?piq:((gq==2)?pu:po));
    pq0=pq[0]; pq1=pq[1]; pq2=pq[2]; pq3=pq[3];
  }

  // phase 2: block = (h-tile n16, batch-tile mt); wave = gate
  const int n16 = blockIdx.x >> 2;
  const int mt = blockIdx.x & 3;
  const int arow2 = mt*16 + col;
  const int r2 = tid >> 4;           // 0..15 (uses whole block: 256 = 16x16)
  const int c2 = tid & 15;
  const int b2 = mt*16 + r2;
  const int h2 = n16*16 + c2;
  const float wl2 = WcLast[h2];
  const float bc2 = bc[h2];
  float creg = 0.f;                  // this thread's cx element, all 256 steps

  __syncthreads();

  const size_t SBH = (size_t)S_LEN*B_SZ*H_SZ;

  for (int s = 0; s < S_LEN; ++s){
    // ================= phase 1: pre + activations + qgate =================
    {
      const __bf16* xrow = xb + (size_t)s*B_SZ*I_SZ + (size_t)arow1*I_SZ + ksub;
      const __bf16* hrow = hxb + (size_t)arow1*H_SZ + ksub;
      f32x4 acc[4] = {{0,0,0,0},{0,0,0,0},{0,0,0,0},{0,0,0,0}};
#pragma unroll 8
      for (int kb=0;kb<16;kb++){
        bf16x8 a = *reinterpret_cast<const bf16x8*>(xrow + kb*32);
        bf16x8 b = *reinterpret_cast<const bf16x8*>(&ldsW[(kb*64 + l)*8]);
        acc[kb&3] = __builtin_amdgcn_mfma_f32_16x16x32_bf16(a, b, acc[kb&3], 0,0,0);
      }
#pragma unroll 8
      for (int kb=16;kb<48;kb++){
        bf16x8 a = *reinterpret_cast<const bf16x8*>(hrow + (kb-16)*32);
        bf16x8 b = *reinterpret_cast<const bf16x8*>(&ldsW[(kb*64 + l)*8]);
        acc[kb&3] = __builtin_amdgcn_mfma_f32_16x16x32_bf16(a, b, acc[kb&3], 0,0,0);
      }
      f32x4 r = (acc[0]+acc[1])+(acc[2]+acc[3]);
      float pr[4];
#pragma unroll
      for (int rr=0;rr<4;rr++){
        int brow = wave*16 + ((l>>4)<<2) + rr;
        float p = r[rr] + bias1;
        pr[rr] = p;
        float a = isU1 ? tanhf(p) : sigmoidf_(p);
        act[((size_t)g1*B_SZ + brow)*H_SZ + h1] = (__bf16)a;
      }
      if (isQ){
        if (col < 4){
#pragma unroll
          for (int rr=0;rr<4;rr++){
            int brow = wave*16 + ((l>>4)<<2) + rr;
            pre4[brow][col] = pr[rr];
          }
        }
        __syncthreads();
        if (tid < 64){
          float th = pre4[tid][0]*pq0 + pre4[tid][1]*pq1 + pre4[tid][2]*pq2 + pre4[tid][3]*pq3;
          float z = cosf(2.f*th);
          zact[gq*B_SZ + tid] = (gq==2) ? z : sigmoidf_(z);
        }
      }
    }

    grid_sync(bar_cnt, bar_gen);

    // ================= phase 2: comb + cell update =================
    {
      const __bf16* a2 = act + ((size_t)wave*B_SZ + arow2)*H_SZ + ksub;  // wave = gate
      f32x4 acc[4] = {{0,0,0,0},{0,0,0,0},{0,0,0,0},{0,0,0,0}};
#pragma unroll 8
      for (int kb=0;kb<32;kb++){
        bf16x8 a = *reinterpret_cast<const bf16x8*>(a2 + kb*32);
        bf16x8 b = *reinterpret_cast<const bf16x8*>(&ldsWc[(kb*64 + l)*8]);
        acc[kb&3] = __builtin_amdgcn_mfma_f32_16x16x32_bf16(a, b, acc[kb&3], 0,0,0);
      }
      f32x4 r = (acc[0]+acc[1])+(acc[2]+acc[3]);
#pragma unroll
      for (int rr=0;rr<4;rr++){
        int row = ((l>>4)<<2) + rr;
        gx[wave][row][col] = r[rr];
      }
      __syncthreads();
      float zf = zact[      b2], zi = zact[ 64+b2];
      float zu = zact[128 + b2], zo = zact[192+b2];
      float fg = sigmoidf_(gx[0][r2][c2] + bc2 + zf*wl2);
      float ig = sigmoidf_(gx[1][r2][c2] + bc2 + zi*wl2);
      float gg = tanhf(    gx[2][r2][c2] + bc2 + zu*wl2);
      float og = sigmoidf_(gx[3][r2][c2] + bc2 + zo*wl2);
      float cn = fg*creg + ig*gg;
      creg = cn;
      float hn = og*tanhf(cn);
      size_t idx = (size_t)b2*H_SZ + h2;
      hxb[idx] = (__bf16)hn;
      out[(size_t)s*B_SZ*H_SZ + idx] = hn;
      if (s == S_LEN-1){
        out[SBH + idx] = hn;
        out[SBH + (size_t)B_SZ*H_SZ + idx] = cn;
      }
    }

    grid_sync(bar_cnt, bar_gen);
  }
}

// ---------------- launch ----------------

extern "C" void kernel_launch(void* const* d_in, const int* in_sizes, int n_in,
                              void* d_out, int out_size, void* d_ws, size_t ws_size,
                              hipStream_t stream){
  const float* inputs = (const float*)d_in[0];
  const float* Wf  = (const float*)d_in[1];
  const float* bf_ = (const float*)d_in[2];
  const float* Wi  = (const float*)d_in[3];
  const float* bi_ = (const float*)d_in[4];
  const float* Wu  = (const float*)d_in[5];
  const float* bu_ = (const float*)d_in[6];
  const float* Wo  = (const float*)d_in[7];
  const float* bo_ = (const float*)d_in[8];
  const float* pf  = (const float*)d_in[9];
  const float* piq = (const float*)d_in[10];
  const float* pu  = (const float*)d_in[11];
  const float* po  = (const float*)d_in[12];
  const float* Wc  = (const float*)d_in[13];
  const float* bc  = (const float*)d_in[14];
  float* out = (float*)d_out;

  __bf16* W4p = (__bf16*)d_ws;                        // 6,291,456 bf16
  __bf16* Wcp = W4p + (size_t)256*48*64*8;            // 1,048,576 bf16
  __bf16* xb  = Wcp + (size_t)64*32*64*8;             // 8,388,608 bf16
  __bf16* act = xb  + (size_t)S_LEN*B_SZ*I_SZ;        // 262,144 bf16
  __bf16* hxb = act + (size_t)4*B_SZ*H_SZ;            // 65,536 bf16
  float*  zact = (float*)(hxb + (size_t)B_SZ*H_SZ);   // 256 f32
  unsigned* bar = (unsigned*)(zact + 256);            // 2 u32

  pack_w4_k<<<256*48, 64, 0, stream>>>(Wf, Wi, Wu, Wo, W4p);
  pack_wc_k<<<64*32, 64, 0, stream>>>(Wc, Wcp);
  cast_x_k<<<2048, 256, 0, stream>>>(inputs, xb, S_LEN*B_SZ*I_SZ);
  init_h_k<<<256, 256, 0, stream>>>(hxb);
  hipMemsetAsync(bar, 0, 2*sizeof(unsigned), stream);

  qlstm_persist_k<<<NBLK, 256, 0, stream>>>(
      xb, hxb, W4p, Wcp, bf_, bi_, bu_, bo_, pf, piq, pu, po,
      Wc + (size_t)H_SZ*H_SZ, bc, act, zact, out, bar, bar + 1);
}

// Round 3
// 6518.285 us; speedup vs baseline: 1.3419x; 1.3338x over previous
//
#include <hip/hip_runtime.h>

#define S_LEN 256
#define B_SZ 64
#define I_SZ 512
#define H_SZ 1024
#define NBLK 256

typedef __bf16 bf16x8 __attribute__((ext_vector_type(8)));
typedef float f32x4 __attribute__((ext_vector_type(4)));

__device__ __forceinline__ float sigmoidf_(float x){ return 1.f/(1.f + expf(-x)); }

// ---- device-coherent (MALL) access helpers: bypass L1+L2, no fences ----
// 16B fragment = 2x 8B relaxed agent atomic loads (compiler tracks vmcnt -> pipelined)
__device__ __forceinline__ bf16x8 ld_cc(const __bf16* p){
  const unsigned long long* q = (const unsigned long long*)p;
  unsigned long long lo = __hip_atomic_load(q,   __ATOMIC_RELAXED, __HIP_MEMORY_SCOPE_AGENT);
  unsigned long long hi = __hip_atomic_load(q+1, __ATOMIC_RELAXED, __HIP_MEMORY_SCOPE_AGENT);
  union { unsigned long long u[2]; bf16x8 v; } u; u.u[0]=lo; u.u[1]=hi; return u.v;
}
__device__ __forceinline__ void st_cc16(__bf16* p, __bf16 v){
  unsigned short b = __builtin_bit_cast(unsigned short, v);
  __hip_atomic_store((unsigned short*)p, b, __ATOMIC_RELAXED, __HIP_MEMORY_SCOPE_AGENT);
}
__device__ __forceinline__ void st_cc32(float* p, float v){
  __hip_atomic_store(p, v, __ATOMIC_RELAXED, __HIP_MEMORY_SCOPE_AGENT);
}
__device__ __forceinline__ float ld_cc32(const float* p){
  return __hip_atomic_load(p, __ATOMIC_RELAXED, __HIP_MEMORY_SCOPE_AGENT);
}

// ---------------- prep kernels ----------------

__global__ __launch_bounds__(64) void pack_w4_k(const float* __restrict__ Wf, const float* __restrict__ Wi,
                                                const float* __restrict__ Wu, const float* __restrict__ Wo,
                                                __bf16* __restrict__ W4p){
  int blk = blockIdx.x;           // nt*48 + kb
  int nt = blk / 48, kb = blk % 48;
  int l = threadIdx.x;
  int n = nt*16 + (l & 15);
  int g = n >> 10, h = n & 1023;
  const float* W = (g==0)?Wf:((g==1)?Wi:((g==2)?Wu:Wo));
  int k0 = kb*32 + ((l>>4)<<3);
  __bf16 tmp[8];
#pragma unroll
  for (int j=0;j<8;j++) tmp[j] = (__bf16)W[(size_t)(k0+j)*H_SZ + h];
  *reinterpret_cast<bf16x8*>(W4p + ((size_t)blk*64 + l)*8) = *reinterpret_cast<bf16x8*>(tmp);
}

__global__ __launch_bounds__(64) void pack_wc_k(const float* __restrict__ Wc, __bf16* __restrict__ Wcp){
  int blk = blockIdx.x;           // nt*32 + kb
  int nt = blk / 32, kb = blk % 32;
  int l = threadIdx.x;
  int n = nt*16 + (l & 15);
  int k0 = kb*32 + ((l>>4)<<3);
  __bf16 tmp[8];
#pragma unroll
  for (int j=0;j<8;j++) tmp[j] = (__bf16)Wc[(size_t)(k0+j)*H_SZ + n];
  *reinterpret_cast<bf16x8*>(Wcp + ((size_t)blk*64 + l)*8) = *reinterpret_cast<bf16x8*>(tmp);
}

__global__ void cast_x_k(const float* __restrict__ x, __bf16* __restrict__ xb, int n){
  int stride = gridDim.x * blockDim.x * 4;
  for (int i = (blockIdx.x*blockDim.x + threadIdx.x)*4; i < n; i += stride){
    float4 v = *reinterpret_cast<const float4*>(x + i);
    __bf16 o[4] = {(__bf16)v.x, (__bf16)v.y, (__bf16)v.z, (__bf16)v.w};
    *reinterpret_cast<uint2*>(xb + i) = *reinterpret_cast<const uint2*>(o);
  }
}

__global__ void init_h_k(__bf16* __restrict__ hxb){
  int i = blockIdx.x*blockDim.x + threadIdx.x;   // 65536 threads
  hxb[i] = (__bf16)0.f;
}

// ---------------- fence-free grid barrier ----------------
// All shared data moved with sc0|sc1 (MALL-coherent) ops -> no L2 state to
// flush/invalidate. vmcnt(0) guarantees prior stores reached the coherence
// point before the arrival increment. Counter is monotonic (512*256 < 2^32).
__device__ __forceinline__ void grid_bar(unsigned* cnt, unsigned target){
  __syncthreads();   // per-wave vmcnt(0) before s_barrier drains this block's stores
  if (threadIdx.x == 0){
    asm volatile("s_waitcnt vmcnt(0) lgkmcnt(0)" ::: "memory");
    __hip_atomic_fetch_add(cnt, 1u, __ATOMIC_RELAXED, __HIP_MEMORY_SCOPE_AGENT);
    while (__hip_atomic_load(cnt, __ATOMIC_RELAXED, __HIP_MEMORY_SCOPE_AGENT) < target)
      __builtin_amdgcn_s_sleep(2);
  }
  __syncthreads();
}

// ---------------- persistent kernel: all 256 steps ----------------

__global__ __launch_bounds__(256, 1) void qlstm_persist_k(
    const __bf16* __restrict__ xb,    // (S,B,I) bf16, read-only (L2-cached)
    __bf16* hxb,                      // (B,H) bf16 state, MALL-coherent
    const __bf16* __restrict__ W4p, const __bf16* __restrict__ Wcp,
    const float* __restrict__ bfv, const float* __restrict__ biv,
    const float* __restrict__ buv, const float* __restrict__ bov,
    const float* __restrict__ pf, const float* __restrict__ piq,
    const float* __restrict__ pu, const float* __restrict__ po,
    const float* __restrict__ WcLast, const float* __restrict__ bc,
    __bf16* act, float* zact,         // MALL-coherent exchange buffers
    float* __restrict__ out,          // outputs (S,B,H) + hx (B,H) + cx (B,H)
    unsigned* bar_cnt)
{
  __shared__ __align__(16) __bf16 ldsW[48*64*8];    // 49152 B: phase-1 B frags
  __shared__ __align__(16) __bf16 ldsWc[32*64*8];   // 32768 B: phase-2 Wc frags
  __shared__ float gx[4][16][16];                   // gate exchange
  __shared__ float pre4[64][4];                     // qgate pre-activations

  const int tid = threadIdx.x;
  const int wave = tid >> 6;
  const int l = tid & 63;
  const int col = l & 15;
  const int ksub = (l >> 4) * 8;

  // ---- stage weights to LDS once ----
  {
    const __bf16* src = W4p + (size_t)blockIdx.x*48*64*8;
    for (int i = tid; i < 48*64; i += 256)
      *reinterpret_cast<bf16x8*>(&ldsW[(size_t)i*8]) = *reinterpret_cast<const bf16x8*>(src + (size_t)i*8);
    const int n16s = blockIdx.x >> 2;
    const __bf16* src2 = Wcp + (size_t)n16s*32*64*8;
    for (int i = tid; i < 32*64; i += 256)
      *reinterpret_cast<bf16x8*>(&ldsWc[(size_t)i*8]) = *reinterpret_cast<const bf16x8*>(src2 + (size_t)i*8);
  }

  // ---- per-thread constants ----
  const int n1 = blockIdx.x*16 + col;
  const int g1 = n1 >> 10;
  const int h1 = n1 & 1023;
  const float* bptr = (g1==0)?bfv:((g1==1)?biv:((g1==2)?buv:bov));
  const float bias1 = bptr[h1];
  const bool isU1 = (g1==2);
  const int arow1 = wave*16 + col;

  const bool isQ = ((blockIdx.x & 63) == 0);
  const int gq = blockIdx.x >> 6;
  float pq0=0.f,pq1=0.f,pq2=0.f,pq3=0.f;
  if (isQ){
    const float* pq = (gq==0)?pf:((gq==1)?piq:((gq==2)?pu:po));
    pq0=pq[0]; pq1=pq[1]; pq2=pq[2]; pq3=pq[3];
  }

  const int n16 = blockIdx.x >> 2;
  const int mt = blockIdx.x & 3;
  const int arow2 = mt*16 + col;
  const int r2 = tid >> 4;
  const int c2 = tid & 15;
  const int b2 = mt*16 + r2;
  const int h2 = n16*16 + c2;
  const float wl2 = WcLast[h2];
  const float bc2 = bc[h2];
  float creg = 0.f;                  // this thread's cx element, all 256 steps

  __syncthreads();

  const size_t SBH = (size_t)S_LEN*B_SZ*H_SZ;
  unsigned bar_t = 0;

  for (int s = 0; s < S_LEN; ++s){
    // ================= phase 1: pre + activations + qgate =================
    {
      const __bf16* xrow = xb + (size_t)s*B_SZ*I_SZ + (size_t)arow1*I_SZ + ksub;
      const __bf16* hrow = hxb + (size_t)arow1*H_SZ + ksub;
      f32x4 acc[4] = {{0,0,0,0},{0,0,0,0},{0,0,0,0},{0,0,0,0}};

      // issue first hx chunk (MALL latency hides under x-part compute)
      bf16x8 hfA[8], hfB[8];
#pragma unroll
      for (int j=0;j<8;j++) hfA[j] = ld_cc(hrow + j*32);

      // x part: kb 0..15, normal loads (read-only, L2-cached)
#pragma unroll
      for (int kb=0;kb<16;kb++){
        bf16x8 a = *reinterpret_cast<const bf16x8*>(xrow + kb*32);
        bf16x8 b = *reinterpret_cast<const bf16x8*>(&ldsW[(kb*64 + l)*8]);
        acc[kb&3] = __builtin_amdgcn_mfma_f32_16x16x32_bf16(a, b, acc[kb&3], 0,0,0);
      }
      // hx part: kb 16..47, chunked double-buffer of MALL-coherent loads
#pragma unroll
      for (int c=0;c<4;c++){
        bf16x8* cur = (c&1) ? hfB : hfA;
        bf16x8* nxt = (c&1) ? hfA : hfB;
        if (c<3){
#pragma unroll
          for (int j=0;j<8;j++) nxt[j] = ld_cc(hrow + ((c+1)*8+j)*32);
        }
#pragma unroll
        for (int j=0;j<8;j++){
          int kb = 16 + c*8 + j;
          bf16x8 b = *reinterpret_cast<const bf16x8*>(&ldsW[(kb*64 + l)*8]);
          acc[kb&3] = __builtin_amdgcn_mfma_f32_16x16x32_bf16(cur[j], b, acc[kb&3], 0,0,0);
        }
      }
      f32x4 r = (acc[0]+acc[1])+(acc[2]+acc[3]);
      float pr[4];
#pragma unroll
      for (int rr=0;rr<4;rr++){
        int brow = wave*16 + ((l>>4)<<2) + rr;
        float p = r[rr] + bias1;
        pr[rr] = p;
        float a = isU1 ? tanhf(p) : sigmoidf_(p);
        st_cc16(&act[((size_t)g1*B_SZ + brow)*H_SZ + h1], (__bf16)a);
      }
      if (isQ){
        if (col < 4){
#pragma unroll
          for (int rr=0;rr<4;rr++){
            int brow = wave*16 + ((l>>4)<<2) + rr;
            pre4[brow][col] = pr[rr];
          }
        }
        __syncthreads();
        if (tid < 64){
          float th = pre4[tid][0]*pq0 + pre4[tid][1]*pq1 + pre4[tid][2]*pq2 + pre4[tid][3]*pq3;
          float z = cosf(2.f*th);
          st_cc32(&zact[gq*B_SZ + tid], (gq==2) ? z : sigmoidf_(z));
        }
      }
    }

    bar_t += NBLK;
    grid_bar(bar_cnt, bar_t);

    // ================= phase 2: comb + cell update =================
    {
      // zact loads issued early (ready since before barrier)
      float zf = ld_cc32(&zact[      b2]);
      float zi = ld_cc32(&zact[ 64 + b2]);
      float zu = ld_cc32(&zact[128 + b2]);
      float zo = ld_cc32(&zact[192 + b2]);

      const __bf16* a2 = act + ((size_t)wave*B_SZ + arow2)*H_SZ + ksub;  // wave = gate
      f32x4 acc[4] = {{0,0,0,0},{0,0,0,0},{0,0,0,0},{0,0,0,0}};
      bf16x8 afA[8], afB[8];
#pragma unroll
      for (int j=0;j<8;j++) afA[j] = ld_cc(a2 + j*32);
#pragma unroll
      for (int c=0;c<4;c++){
        bf16x8* cur = (c&1) ? afB : afA;
        bf16x8* nxt = (c&1) ? afA : afB;
        if (c<3){
#pragma unroll
          for (int j=0;j<8;j++) nxt[j] = ld_cc(a2 + ((c+1)*8+j)*32);
        }
#pragma unroll
        for (int j=0;j<8;j++){
          int kb = c*8 + j;
          bf16x8 b = *reinterpret_cast<const bf16x8*>(&ldsWc[(kb*64 + l)*8]);
          acc[kb&3] = __builtin_amdgcn_mfma_f32_16x16x32_bf16(cur[j], b, acc[kb&3], 0,0,0);
        }
      }
      f32x4 r = (acc[0]+acc[1])+(acc[2]+acc[3]);
#pragma unroll
      for (int rr=0;rr<4;rr++){
        int row = ((l>>4)<<2) + rr;
        gx[wave][row][col] = r[rr];
      }
      __syncthreads();
      float fg = sigmoidf_(gx[0][r2][c2] + bc2 + zf*wl2);
      float ig = sigmoidf_(gx[1][r2][c2] + bc2 + zi*wl2);
      float gg = tanhf(    gx[2][r2][c2] + bc2 + zu*wl2);
      float og = sigmoidf_(gx[3][r2][c2] + bc2 + zo*wl2);
      float cn = fg*creg + ig*gg;
      creg = cn;
      float hn = og*tanhf(cn);
      size_t idx = (size_t)b2*H_SZ + h2;
      st_cc16(&hxb[idx], (__bf16)hn);
      __builtin_nontemporal_store(hn, &out[(size_t)s*B_SZ*H_SZ + idx]);
      if (s == S_LEN-1){
        __builtin_nontemporal_store(hn, &out[SBH + idx]);
        __builtin_nontemporal_store(cn, &out[SBH + (size_t)B_SZ*H_SZ + idx]);
      }
    }

    bar_t += NBLK;
    grid_bar(bar_cnt, bar_t);
  }
}

// ---------------- launch ----------------

extern "C" void kernel_launch(void* const* d_in, const int* in_sizes, int n_in,
                              void* d_out, int out_size, void* d_ws, size_t ws_size,
                              hipStream_t stream){
  const float* inputs = (const float*)d_in[0];
  const float* Wf  = (const float*)d_in[1];
  const float* bf_ = (const float*)d_in[2];
  const float* Wi  = (const float*)d_in[3];
  const float* bi_ = (const float*)d_in[4];
  const float* Wu  = (const float*)d_in[5];
  const float* bu_ = (const float*)d_in[6];
  const float* Wo  = (const float*)d_in[7];
  const float* bo_ = (const float*)d_in[8];
  const float* pf  = (const float*)d_in[9];
  const float* piq = (const float*)d_in[10];
  const float* pu  = (const float*)d_in[11];
  const float* po  = (const float*)d_in[12];
  const float* Wc  = (const float*)d_in[13];
  const float* bc  = (const float*)d_in[14];
  float* out = (float*)d_out;

  __bf16* W4p = (__bf16*)d_ws;                        // 6,291,456 bf16
  __bf16* Wcp = W4p + (size_t)256*48*64*8;            // 1,048,576 bf16
  __bf16* xb  = Wcp + (size_t)64*32*64*8;             // 8,388,608 bf16
  __bf16* act = xb  + (size_t)S_LEN*B_SZ*I_SZ;        // 262,144 bf16
  __bf16* hxb = act + (size_t)4*B_SZ*H_SZ;            // 65,536 bf16
  float*  zact = (float*)(hxb + (size_t)B_SZ*H_SZ);   // 256 f32
  unsigned* bar = (unsigned*)(zact + 256);            // 1 u32 (monotonic)

  pack_w4_k<<<256*48, 64, 0, stream>>>(Wf, Wi, Wu, Wo, W4p);
  pack_wc_k<<<64*32, 64, 0, stream>>>(Wc, Wcp);
  cast_x_k<<<2048, 256, 0, stream>>>(inputs, xb, S_LEN*B_SZ*I_SZ);
  init_h_k<<<256, 256, 0, stream>>>(hxb);
  hipMemsetAsync(bar, 0, sizeof(unsigned), stream);

  qlstm_persist_k<<<NBLK, 256, 0, stream>>>(
      xb, hxb, W4p, Wcp, bf_, bi_, bu_, bo_, pf, piq, pu, po,
      Wc + (size_t)H_SZ*H_SZ, bc, act, zact, out, bar);
}

// Round 4
// 3507.653 us; speedup vs baseline: 2.4937x; 1.8583x over previous
//
#include <hip/hip_runtime.h>

#define S_LEN 256
#define B_SZ 64
#define I_SZ 512
#define H_SZ 1024
#define NBLK 256

typedef __bf16 bf16x8 __attribute__((ext_vector_type(8)));
typedef float f32x4 __attribute__((ext_vector_type(4)));
typedef unsigned long long u64;

__device__ __forceinline__ float sigmoidf_(float x){ return 1.f/(1.f + expf(-x)); }

// ---- device-coherent (MALL) access helpers: bypass L1+L2, no fences ----
__device__ __forceinline__ u64 ld_cc64(const u64* p){
  return __hip_atomic_load(p, __ATOMIC_RELAXED, __HIP_MEMORY_SCOPE_AGENT);
}
__device__ __forceinline__ void st_cc16(__bf16* p, __bf16 v){
  unsigned short b = __builtin_bit_cast(unsigned short, v);
  __hip_atomic_store((unsigned short*)p, b, __ATOMIC_RELAXED, __HIP_MEMORY_SCOPE_AGENT);
}
__device__ __forceinline__ void st_cc32(float* p, float v){
  __hip_atomic_store(p, v, __ATOMIC_RELAXED, __HIP_MEMORY_SCOPE_AGENT);
}
__device__ __forceinline__ float ld_cc32f(const float* p){
  return __hip_atomic_load(p, __ATOMIC_RELAXED, __HIP_MEMORY_SCOPE_AGENT);
}

// ---------------- prep kernels ----------------

__global__ __launch_bounds__(64) void pack_w4_k(const float* __restrict__ Wf, const float* __restrict__ Wi,
                                                const float* __restrict__ Wu, const float* __restrict__ Wo,
                                                __bf16* __restrict__ W4p){
  int blk = blockIdx.x;           // nt16*48 + kb
  int nt = blk / 48, kb = blk % 48;
  int l = threadIdx.x;
  int n = nt*16 + (l & 15);
  int g = n >> 10, h = n & 1023;
  const float* W = (g==0)?Wf:((g==1)?Wi:((g==2)?Wu:Wo));
  int k0 = kb*32 + ((l>>4)<<3);
  __bf16 tmp[8];
#pragma unroll
  for (int j=0;j<8;j++) tmp[j] = (__bf16)W[(size_t)(k0+j)*H_SZ + h];
  *reinterpret_cast<bf16x8*>(W4p + ((size_t)blk*64 + l)*8) = *reinterpret_cast<bf16x8*>(tmp);
}

__global__ __launch_bounds__(64) void pack_wc_k(const float* __restrict__ Wc, __bf16* __restrict__ Wcp){
  int blk = blockIdx.x;           // nt16*32 + kb
  int nt = blk / 32, kb = blk % 32;
  int l = threadIdx.x;
  int n = nt*16 + (l & 15);
  int k0 = kb*32 + ((l>>4)<<3);
  __bf16 tmp[8];
#pragma unroll
  for (int j=0;j<8;j++) tmp[j] = (__bf16)Wc[(size_t)(k0+j)*H_SZ + n];
  *reinterpret_cast<bf16x8*>(Wcp + ((size_t)blk*64 + l)*8) = *reinterpret_cast<bf16x8*>(tmp);
}

__global__ void cast_x_k(const float* __restrict__ x, __bf16* __restrict__ xb, int n){
  int stride = gridDim.x * blockDim.x * 4;
  for (int i = (blockIdx.x*blockDim.x + threadIdx.x)*4; i < n; i += stride){
    float4 v = *reinterpret_cast<const float4*>(x + i);
    __bf16 o[4] = {(__bf16)v.x, (__bf16)v.y, (__bf16)v.z, (__bf16)v.w};
    *reinterpret_cast<uint2*>(xb + i) = *reinterpret_cast<const uint2*>(o);
  }
}

__global__ void init_h_k(__bf16* __restrict__ hxb){
  int i = blockIdx.x*blockDim.x + threadIdx.x;   // 65536 threads
  hxb[i] = (__bf16)0.f;
}

// ---------------- flag-array grid barrier (no RMW contention) ----------------
// Each block stores monotonic epoch to its own flag; wave 0 polls all 256.
// __syncthreads drains vmcnt(0) per wave -> all sc0sc1 data stores are at the
// coherence point before the flag store issues.
__device__ __forceinline__ void flag_bar(unsigned* flags, unsigned target){
  asm volatile("" ::: "memory");
  __syncthreads();
  if (threadIdx.x == 0)
    __hip_atomic_store(&flags[blockIdx.x], target, __ATOMIC_RELAXED, __HIP_MEMORY_SCOPE_AGENT);
  if (threadIdx.x < 64){
    const u64* f = (const u64*)flags;
    int i0 = (int)threadIdx.x * 2;
    for(;;){
      u64 a = __hip_atomic_load(f+i0,   __ATOMIC_RELAXED, __HIP_MEMORY_SCOPE_AGENT);
      u64 b = __hip_atomic_load(f+i0+1, __ATOMIC_RELAXED, __HIP_MEMORY_SCOPE_AGENT);
      bool ok = ((unsigned)a >= target) && ((unsigned)(a>>32) >= target)
             && ((unsigned)b >= target) && ((unsigned)(b>>32) >= target);
      if (__all(ok)) break;
      __builtin_amdgcn_s_sleep(1);
    }
  }
  __syncthreads();
}

// ---------------- persistent kernel: all 256 steps ----------------
// Phase 1: blocks = 4 mt (16 rows) x 64 nt64 (64 cols); wave owns a 16-col tile,
//          W4 fragments live in 192 VGPRs/lane; hx staged via LDS (32 KB/block).
// Phase 2: blocks = 8 mt2 (8 rows) x 32 ht (32 h-cols); wave = gate;
//          act staged via LDS (64 KB/block); Wc resident in LDS (64 KB).

__global__ __launch_bounds__(256, 1) void qlstm_persist_k(
    const __bf16* __restrict__ xb,
    __bf16* hxb,
    const __bf16* __restrict__ W4p, const __bf16* __restrict__ Wcp,
    const float* __restrict__ bfv, const float* __restrict__ biv,
    const float* __restrict__ buv, const float* __restrict__ bov,
    const float* __restrict__ pf, const float* __restrict__ piq,
    const float* __restrict__ pu, const float* __restrict__ po,
    const float* __restrict__ WcLast, const float* __restrict__ bc,
    __bf16* act, float* zact,
    float* __restrict__ out,
    unsigned* flags)
{
  __shared__ __align__(16) __bf16 ldsWc[2*32*64*8];   // 64 KiB, persistent
  __shared__ __align__(16) __bf16 ldsStage[32][1032]; // 66 KiB, padded rows (hx: 16, act: 32)
  __shared__ float gx[4][8][32];
  __shared__ float pre4[16][4];

  const int tid = threadIdx.x;
  const int bid = blockIdx.x;
  const int wave = tid >> 6;
  const int l = tid & 63;
  const int col = l & 15;
  const int ksub8 = (l >> 4) * 8;          // A/B fragment k-offset (elems)

  // ---- phase-1 ids ----
  const int mt1 = bid >> 6;                // 0..3, 16 batch rows
  const int nt64 = bid & 63;               // 64-col supertile
  const int nt16 = nt64*4 + wave;          // this wave's 16-col tile
  const int g1 = nt16 >> 6;
  const int h1 = (nt16*16 + col) & 1023;

  // ---- phase-2 ids ----
  const int mt2 = bid >> 5;                // 0..7, 8 batch rows
  const int ht  = bid & 31;                // 32 h-cols
  const int r2 = tid >> 5;                 // 0..7
  const int c2 = tid & 31;
  const int b2 = mt2*8 + r2;
  const int h2 = ht*32 + c2;

  // ---- W4 fragments -> registers (48 x bf16x8 = 192 VGPR) ----
  bf16x8 wfrag[48];
  {
    const bf16x8* src = (const bf16x8*)(W4p + ((size_t)nt16*48*64 + (size_t)l)*8);
#pragma unroll
    for (int kb=0;kb<48;kb++) wfrag[kb] = src[(size_t)kb*64];
  }
  // ---- Wc -> LDS (persistent) ----
  {
    const u64* src = (const u64*)(Wcp + (size_t)ht*2*32*64*8);
    u64* dst = (u64*)ldsWc;
    for (int i = tid; i < 8192; i += 256) dst[i] = src[i];
  }

  const float* bptr = (g1==0)?bfv:((g1==1)?biv:((g1==2)?buv:bov));
  const float bias1 = bptr[h1];
  const bool isU1 = (g1==2);
  const bool isQb = ((nt64 & 15) == 0);    // wave 0 covers gate cols 0..15
  const int gq = nt64 >> 4;
  float pq0=0.f,pq1=0.f,pq2=0.f,pq3=0.f;
  if (isQb && wave==0){
    const float* pq = (gq==0)?pf:((gq==1)?piq:((gq==2)?pu:po));
    pq0=pq[0]; pq1=pq[1]; pq2=pq[2]; pq3=pq[3];
  }

  const float wl2 = WcLast[h2];
  const float bc2 = bc[h2];
  float creg = 0.f;

  __syncthreads();   // Wc staged

  const size_t SBH = (size_t)S_LEN*B_SZ*H_SZ;
  char* stageB = (char*)&ldsStage[0][0];

  for (int s = 0; s < S_LEN; ++s){
    // ================= phase 1 =================
    {
      // stage hx rows [mt1*16, mt1*16+16) -> LDS (all loads in flight, one drain)
      const u64* hsrc = (const u64*)(hxb + (size_t)mt1*16*H_SZ);
      u64 tmp[16];
#pragma unroll
      for (int j=0;j<16;j++) tmp[j] = ld_cc64(hsrc + j*256 + tid);

      // x A-fragments (L2-cached, read-only)
      const __bf16* xrow = xb + ((size_t)s*B_SZ + (size_t)(mt1*16 + col))*I_SZ + ksub8;
      bf16x8 xf[16];
#pragma unroll
      for (int kb=0;kb<16;kb++) xf[kb] = *reinterpret_cast<const bf16x8*>(xrow + kb*32);

#pragma unroll
      for (int j=0;j<16;j++){
        int flat = (j*256 + tid)*8;        // byte offset in the 32 KB slice
        int row = flat >> 11;
        int within = flat & 2047;
        *(u64*)(stageB + row*2064 + within) = tmp[j];
      }
      __syncthreads();

      f32x4 acc[4] = {{0,0,0,0},{0,0,0,0},{0,0,0,0},{0,0,0,0}};
#pragma unroll
      for (int kb=0;kb<16;kb++)
        acc[kb&3] = __builtin_amdgcn_mfma_f32_16x16x32_bf16(xf[kb], wfrag[kb], acc[kb&3], 0,0,0);
      const char* abase = stageB + col*2064 + ksub8*2;
#pragma unroll
      for (int kb=16;kb<48;kb++){
        bf16x8 a = *reinterpret_cast<const bf16x8*>(abase + (kb-16)*64);
        acc[kb&3] = __builtin_amdgcn_mfma_f32_16x16x32_bf16(a, wfrag[kb], acc[kb&3], 0,0,0);
      }
      f32x4 r = (acc[0]+acc[1])+(acc[2]+acc[3]);
      float pr[4];
#pragma unroll
      for (int rr=0;rr<4;rr++){
        int brow = mt1*16 + ((l>>4)<<2) + rr;
        float p = r[rr] + bias1;
        pr[rr] = p;
        float a = isU1 ? tanhf(p) : sigmoidf_(p);
        st_cc16(&act[((size_t)g1*B_SZ + brow)*H_SZ + h1], (__bf16)a);
      }
      if (isQb && wave==0){
        if (col < 4){
#pragma unroll
          for (int rr=0;rr<4;rr++) pre4[((l>>4)<<2)+rr][col] = pr[rr];
        }
        if (l < 16){
          float th = pre4[l][0]*pq0 + pre4[l][1]*pq1 + pre4[l][2]*pq2 + pre4[l][3]*pq3;
          float z = cosf(2.f*th);
          st_cc32(&zact[gq*B_SZ + mt1*16 + l], (gq==2) ? z : sigmoidf_(z));
        }
      }
    }

    flag_bar(flags, (unsigned)(2*s+1));

    // ================= phase 2 =================
    {
      // stage act[g][mt2*8 .. +8][0..1024) -> LDS rows g*8+r
      u64 tmp[32];
#pragma unroll
      for (int g=0; g<4; g++){
        const u64* asrc = (const u64*)(act + ((size_t)g*B_SZ + (size_t)mt2*8)*H_SZ);
#pragma unroll
        for (int j=0;j<8;j++) tmp[g*8+j] = ld_cc64(asrc + j*256 + tid);
      }
#pragma unroll
      for (int g=0; g<4; g++){
#pragma unroll
        for (int j=0;j<8;j++){
          int flat = (j*256 + tid)*8;
          int row = flat >> 11;            // 0..7
          int within = flat & 2047;
          *(u64*)(stageB + (g*8+row)*2064 + within) = tmp[g*8+j];
        }
      }
      __syncthreads();

      // wave = gate; compute full comb for 8 rows x 32 cols
      f32x4 acc2[4] = {{0,0,0,0},{0,0,0,0},{0,0,0,0},{0,0,0,0}};
      const char* a2base = stageB + (wave*8 + (col&7))*2064 + ksub8*2;
      const bf16x8* bf0 = (const bf16x8*)ldsWc + l;
      const bf16x8* bf1 = (const bf16x8*)ldsWc + 32*64 + l;
#pragma unroll
      for (int kb=0;kb<32;kb++){
        bf16x8 a = *reinterpret_cast<const bf16x8*>(a2base + kb*64);
        acc2[kb&1]     = __builtin_amdgcn_mfma_f32_16x16x32_bf16(a, bf0[(size_t)kb*64], acc2[kb&1], 0,0,0);
        acc2[2+(kb&1)] = __builtin_amdgcn_mfma_f32_16x16x32_bf16(a, bf1[(size_t)kb*64], acc2[2+(kb&1)], 0,0,0);
      }
      f32x4 rA = acc2[0]+acc2[1];
      f32x4 rB = acc2[2]+acc2[3];
#pragma unroll
      for (int rr=0;rr<4;rr++){
        int row = ((l>>4)<<2) + rr;
        if (row < 8){
          gx[wave][row][col]      = rA[rr];
          gx[wave][row][16 + col] = rB[rr];
        }
      }
      float zf = ld_cc32f(&zact[      b2]);
      float zi = ld_cc32f(&zact[ 64 + b2]);
      float zu = ld_cc32f(&zact[128 + b2]);
      float zo = ld_cc32f(&zact[192 + b2]);
      __syncthreads();

      float fg = sigmoidf_(gx[0][r2][c2] + bc2 + zf*wl2);
      float ig = sigmoidf_(gx[1][r2][c2] + bc2 + zi*wl2);
      float gg = tanhf(    gx[2][r2][c2] + bc2 + zu*wl2);
      float og = sigmoidf_(gx[3][r2][c2] + bc2 + zo*wl2);
      float cn = fg*creg + ig*gg;
      creg = cn;
      float hn = og*tanhf(cn);
      size_t idx = (size_t)b2*H_SZ + h2;
      st_cc16(&hxb[idx], (__bf16)hn);
      __builtin_nontemporal_store(hn, &out[(size_t)s*B_SZ*H_SZ + idx]);
      if (s == S_LEN-1){
        __builtin_nontemporal_store(hn, &out[SBH + idx]);
        __builtin_nontemporal_store(cn, &out[SBH + (size_t)B_SZ*H_SZ + idx]);
      }
    }

    flag_bar(flags, (unsigned)(2*s+2));
  }
}

// ---------------- launch ----------------

extern "C" void kernel_launch(void* const* d_in, const int* in_sizes, int n_in,
                              void* d_out, int out_size, void* d_ws, size_t ws_size,
                              hipStream_t stream){
  const float* inputs = (const float*)d_in[0];
  const float* Wf  = (const float*)d_in[1];
  const float* bf_ = (const float*)d_in[2];
  const float* Wi  = (const float*)d_in[3];
  const float* bi_ = (const float*)d_in[4];
  const float* Wu  = (const float*)d_in[5];
  const float* bu_ = (const float*)d_in[6];
  const float* Wo  = (const float*)d_in[7];
  const float* bo_ = (const float*)d_in[8];
  const float* pf  = (const float*)d_in[9];
  const float* piq = (const float*)d_in[10];
  const float* pu  = (const float*)d_in[11];
  const float* po  = (const float*)d_in[12];
  const float* Wc  = (const float*)d_in[13];
  const float* bc  = (const float*)d_in[14];
  float* out = (float*)d_out;

  __bf16* W4p = (__bf16*)d_ws;                        // 6,291,456 bf16
  __bf16* Wcp = W4p + (size_t)256*48*64*8;            // 1,048,576 bf16
  __bf16* xb  = Wcp + (size_t)64*32*64*8;             // 8,388,608 bf16
  __bf16* act = xb  + (size_t)S_LEN*B_SZ*I_SZ;        // 262,144 bf16
  __bf16* hxb = act + (size_t)4*B_SZ*H_SZ;            // 65,536 bf16
  float*  zact = (float*)(hxb + (size_t)B_SZ*H_SZ);   // 256 f32
  unsigned* flags = (unsigned*)(zact + 256);          // 256 u32

  pack_w4_k<<<256*48, 64, 0, stream>>>(Wf, Wi, Wu, Wo, W4p);
  pack_wc_k<<<64*32, 64, 0, stream>>>(Wc, Wcp);
  cast_x_k<<<2048, 256, 0, stream>>>(inputs, xb, S_LEN*B_SZ*I_SZ);
  init_h_k<<<256, 256, 0, stream>>>(hxb);
  hipMemsetAsync(flags, 0, NBLK*sizeof(unsigned), stream);

  qlstm_persist_k<<<NBLK, 256, 0, stream>>>(
      xb, hxb, W4p, Wcp, bf_, bi_, bu_, bo_, pf, piq, pu, po,
      Wc + (size_t)H_SZ*H_SZ, bc, act, zact, out, flags);
}